// Round 13
// baseline (253.421 us; speedup 1.0000x reference)
//
#include <hip/hip_runtime.h>

#define NNODES 100000
#define NREL 8
#define EMB 64
#define YDIM (NREL * EMB)            // 512
#define NSTRIPS (NNODES / 16)        // 6250, exact
#define G1_BLOCKS 1250               // 5 strips per block, exact
#define NBKT 1563                    // buckets of 64 nodes (last has 32)
#define BCAP 896                     // slots per bucket; lambda=640, +10 sigma

typedef __attribute__((ext_vector_type(8))) short bf16x8;   // 8 bf16 (4 VGPRs)
typedef __attribute__((ext_vector_type(4))) float f32x4;

__device__ inline unsigned short f2bf(float f) {
    union { float f; unsigned u; } v; v.f = f;
    return (unsigned short)((v.u + 0x7FFFu + ((v.u >> 16) & 1u)) >> 16);  // RNE
}
__device__ inline float bf2f(unsigned short u) {
    union { unsigned u; float f; } v; v.u = ((unsigned)u) << 16; return v.f;
}

// ---------------------------------------------------------------------------
// Coarse partition: bucket = 64 consecutive nodes. slots fill densely via
// per-bucket cursor -> full-line HBM writebacks (fix for round-12's 60MB of
// partial-line scatter). Key = (c*8+r) | nloc<<20.
// ---------------------------------------------------------------------------
__global__ void k_part(const int* __restrict__ rows, const int* __restrict__ cols,
                       int* __restrict__ bcnt, int* __restrict__ slots, int E) {
    int e = blockIdx.x * blockDim.x + threadIdx.x;
    if (e >= E) return;
    int row = rows[e];
    int r = row / NNODES;                // magic-mul
    int n = row - r * NNODES;
    int p = atomicAdd(&bcnt[n >> 6], 1);
    if (p < BCAP)
        slots[(n >> 6) * BCAP + p] = (cols[e] << 3) | r | ((n & 63) << 20);
}

// ---------------------------------------------------------------------------
// W prep: pack W into MFMA A-fragment order so k_gemm1's per-block init is
// 8 coalesced 16B loads. (unchanged from round 12)
// ---------------------------------------------------------------------------
__global__ void k_wprep(const float* __restrict__ W, unsigned short* __restrict__ wp) {
    int t = blockIdx.x * blockDim.x + threadIdx.x;   // 0..4095
    int lane = t & 63, ks = (t >> 6) & 1, ft = (t >> 7) & 3, rel = t >> 9;
    const float* src = W + rel * 4096 + (ks * 32 + (lane >> 4) * 8) * EMB
                       + ft * 16 + (lane & 15);
    bf16x8 o;
#pragma unroll
    for (int j = 0; j < 8; ++j) o[j] = (short)f2bf(src[j * EMB]);
    *reinterpret_cast<bf16x8*>(wp + (size_t)t * 8) = o;
}

// ---------------------------------------------------------------------------
// GEMM1 (unchanged from round 12): y[c, r*64+f] = sum_k x[c,k] * W[r,k,f].
// ---------------------------------------------------------------------------
__global__ __launch_bounds__(512) void k_gemm1(const float* __restrict__ x,
                                               const unsigned short* __restrict__ wp,
                                               unsigned short* __restrict__ y) {
    __shared__ char tile[2][16384];        // bf16 [16][512], swizzled, x2 buffers
    const int tid  = threadIdx.x;
    const int lane = tid & 63;
    const int rel  = tid >> 6;             // wave id = relation
    const int fl   = lane & 15;            // A row (f_local) == B col (c_local)
    const int kgrp = lane >> 4;            // k-group 0..3

    bf16x8 wfrag[4][2];
#pragma unroll
    for (int ft = 0; ft < 4; ++ft)
#pragma unroll
        for (int ks = 0; ks < 2; ++ks)
            wfrag[ft][ks] = *reinterpret_cast<const bf16x8*>(
                wp + (size_t)((rel * 4 + ft) * 2 + ks) * 512 + lane * 8);

    const int wbase = (fl << 10) + (rel << 7) + (kgrp << 3);
    const int wswz  = (fl & 7) << 4;
    int b = 0;

    int strip = blockIdx.x;
    const float* xp = x + (size_t)(strip * 16 + fl) * EMB + kgrp * 8;
    f32x4 xa0 = *reinterpret_cast<const f32x4*>(xp);
    f32x4 xa1 = *reinterpret_cast<const f32x4*>(xp + 4);
    f32x4 xa2 = *reinterpret_cast<const f32x4*>(xp + 32);
    f32x4 xa3 = *reinterpret_cast<const f32x4*>(xp + 36);

    while (strip < NSTRIPS) {
        const int next = strip + G1_BLOCKS;
        f32x4 xn0 = xa0, xn1 = xa1, xn2 = xa2, xn3 = xa3;
        if (next < NSTRIPS) {              // prefetch next strip's x rows
            const float* xq = x + (size_t)(next * 16 + fl) * EMB + kgrp * 8;
            xn0 = *reinterpret_cast<const f32x4*>(xq);
            xn1 = *reinterpret_cast<const f32x4*>(xq + 4);
            xn2 = *reinterpret_cast<const f32x4*>(xq + 32);
            xn3 = *reinterpret_cast<const f32x4*>(xq + 36);
        }

        bf16x8 B0, B1;
#pragma unroll
        for (int j = 0; j < 4; ++j) {
            B0[j] = (short)f2bf(xa0[j]);  B0[j + 4] = (short)f2bf(xa1[j]);
            B1[j] = (short)f2bf(xa2[j]);  B1[j + 4] = (short)f2bf(xa3[j]);
        }

        f32x4 acc[4] = {f32x4{}, f32x4{}, f32x4{}, f32x4{}};
#pragma unroll
        for (int ft = 0; ft < 4; ++ft) {
            acc[ft] = __builtin_amdgcn_mfma_f32_16x16x32_bf16(wfrag[ft][0], B0, acc[ft], 0, 0, 0);
            acc[ft] = __builtin_amdgcn_mfma_f32_16x16x32_bf16(wfrag[ft][1], B1, acc[ft], 0, 0, 0);
        }

        // D[f][c] -> LDS bf16 tile at [c_local=fl][f_glob=rel*64+ft*16+kgrp*4+i]
        char* tb = tile[b];
#pragma unroll
        for (int ft = 0; ft < 4; ++ft) {
            ushort4 o;
            o.x = f2bf(acc[ft][0]); o.y = f2bf(acc[ft][1]);
            o.z = f2bf(acc[ft][2]); o.w = f2bf(acc[ft][3]);
            *reinterpret_cast<ushort4*>(tb + ((wbase + (ft << 5)) ^ wswz)) = o;
        }

        // raw barrier: wait LDS only, do NOT drain global stores (vmcnt)
        __builtin_amdgcn_sched_barrier(0);
        asm volatile("s_waitcnt lgkmcnt(0)" ::: "memory");
        __builtin_amdgcn_s_barrier();
        __builtin_amdgcn_sched_barrier(0);

        // stream tile -> y, fully coalesced 16B/lane, fire-and-forget
#pragma unroll
        for (int h = 0; h < 2; ++h) {
            int u  = tid + h * 512;            // 16B unit 0..1023
            int cl = u >> 6;                   // c_local
            bf16x8 v = *reinterpret_cast<const bf16x8*>(tb + ((u << 4) ^ ((cl & 7) << 4)));
            *reinterpret_cast<bf16x8*>(y + (size_t)(strip * 16 + cl) * YDIM + ((u & 63) << 3)) = v;
        }
        b ^= 1;   // buffer reuse at distance 2 is protected by the barrier chain
        xa0 = xn0; xa1 = xn1; xa2 = xn2; xa3 = xn3;
        strip = next;
    }
}

// ---------------------------------------------------------------------------
// Gather: block = one 64-node bucket (256 thr / 4 waves). Stage bucket keys
// in LDS, build per-node CSR in LDS (count -> wave-0 shfl scan -> cursor
// scatter), then wave w processes nodes w*16..w*16+15: ballot per-rel degree,
// 8-deep readlane y-gather, out = relu(acc) f32.
// ---------------------------------------------------------------------------
__global__ __launch_bounds__(256) void k_gather(const int* __restrict__ bcnt,
                                                const int* __restrict__ slots,
                                                const unsigned short* __restrict__ yb,
                                                float* __restrict__ out) {
    __shared__ int raw[BCAP];
    __shared__ int srt[BCAP];
    __shared__ int cntL[64], offL[64], curL[64];

    const int bkt  = blockIdx.x;
    const int tid  = threadIdx.x;
    const int lane = tid & 63;
    const int wid  = tid >> 6;

    int m = bcnt[bkt];
    if (m > BCAP) m = BCAP;

    for (int i = tid; i < m; i += 256) raw[i] = slots[bkt * BCAP + i];
    if (tid < 64) cntL[tid] = 0;
    __syncthreads();

    for (int i = tid; i < m; i += 256) atomicAdd(&cntL[raw[i] >> 20], 1);
    __syncthreads();

    if (wid == 0) {                        // exclusive scan of 64 counts
        int v = cntL[lane];
        int s = v;
#pragma unroll
        for (int d = 1; d < 64; d <<= 1) { int u = __shfl_up(s, d); if (lane >= d) s += u; }
        offL[lane] = s - v;
        curL[lane] = s - v;
    }
    __syncthreads();

    for (int i = tid; i < m; i += 256) {
        int k = raw[i];
        int p = atomicAdd(&curL[k >> 20], 1);
        srt[p] = k;
    }
    __syncthreads();

    int nlim = NNODES - bkt * 64; if (nlim > 64) nlim = 64;
    for (int i = wid * 16; i < wid * 16 + 16; ++i) {
        if (i >= nlim) break;
        int s = offL[i], d = cntL[i];
        if (d > 64) d = 64;                 // safety; max observed degree ~< 48
        int kv = (lane < d) ? srt[s + lane] : -1;

        // per-relation degree via ballots (r = low 3 bits of key)
        int crv = 0;
        const int myr = lane & 7;
#pragma unroll
        for (int r = 0; r < NREL; ++r) {
            int cr = (int)__popcll(__ballot(kv >= 0 && (kv & 7) == r));
            crv = (myr == r) ? cr : crv;
        }
        float inv8 = (crv > 0) ? __builtin_amdgcn_rcpf((float)crv) : 0.f;
        int inv8b = __float_as_int(inv8);

        float acc = 0.f;
        for (int j0 = 0; j0 < d; j0 += 8) {
#pragma unroll
            for (int u = 0; u < 8; ++u) {
                int j  = j0 + u;
                int jc = j < d ? j : 0;                         // uniform clamp
                int sp = __builtin_amdgcn_readlane(kv, jc) & 0xFFFFF;  // y-row c*8+r
                int ib = __builtin_amdgcn_readlane(inv8b, sp & 7);
                float si = (j < d) ? __int_as_float(ib) : 0.f;  // dead edge -> *0
                float v  = bf2f(yb[(size_t)sp * EMB + lane]);
                acc = fmaf(si, v, acc);
            }
        }
        out[(size_t)(bkt * 64 + i) * EMB + lane] = fmaxf(acc, 0.f);
    }
}

// ---------------------------------------------------------------------------
extern "C" void kernel_launch(void* const* d_in, const int* in_sizes, int n_in,
                              void* d_out, int out_size, void* d_ws, size_t ws_size,
                              hipStream_t stream) {
    const float* x    = (const float*)d_in[0];
    const float* w    = (const float*)d_in[1];
    const int*   rows = (const int*)d_in[2];   // JAX x64-disabled -> int32
    const int*   cols = (const int*)d_in[3];
    float*       out  = (float*)d_out;
    int E = in_sizes[2];

    char* ws = (char*)d_ws;
    int*            bcnt  = (int*)(ws);                       // 6.3 KB (pad 8KB)
    int*            slots = (int*)(ws + 8192);                // 5.6 MB
    unsigned short* wp    = (unsigned short*)(ws + 5609984);  // 64 KB
    unsigned short* y     = (unsigned short*)(ws + 5675520);  // 102.4 MB

    hipMemsetAsync(bcnt, 0, (size_t)NBKT * sizeof(int), stream);

    k_wprep<<<16, 256, 0, stream>>>(w, wp);
    k_part<<<(E + 255) / 256, 256, 0, stream>>>(rows, cols, bcnt, slots, E);
    k_gemm1<<<G1_BLOCKS, 512, 0, stream>>>(x, wp, y);
    k_gather<<<NBKT, 256, 0, stream>>>(bcnt, slots, y, out);
}

// Round 14
// 140.085 us; speedup vs baseline: 1.8090x; 1.8090x over previous
//
#include <hip/hip_runtime.h>

#define NNODES 100000
#define NREL 8
#define EMB 64
#define YDIM (NREL * EMB)            // 512
#define NSTRIPS (NNODES / 16)        // 6250, exact
#define G1_BLOCKS 1250               // 5 strips per block, exact
#define GNODES 128                   // nodes per coarse bucket
#define NBUCK 782                    // ceil(NNODES/128)
#define CHUNK 4096                   // edges per scatter block

typedef __attribute__((ext_vector_type(8))) short bf16x8;   // 8 bf16 (4 VGPRs)
typedef __attribute__((ext_vector_type(4))) float f32x4;

__device__ inline unsigned short f2bf(float f) {
    union { float f; unsigned u; } v; v.f = f;
    return (unsigned short)((v.u + 0x7FFFu + ((v.u >> 16) & 1u)) >> 16);  // RNE
}
__device__ inline float bf2f(unsigned short u) {
    union { unsigned u; float f; } v; v.u = ((unsigned)u) << 16; return v.f;
}

// ---------------------------------------------------------------------------
// Pass 1: exact bucket histogram (LDS-aggregated; ~245 global atomics/counter)
// ---------------------------------------------------------------------------
__global__ __launch_bounds__(256) void k_count(const int* __restrict__ rows,
                                               int* __restrict__ gcnt, int E) {
    __shared__ int hist[NBUCK];
    for (int i = threadIdx.x; i < NBUCK; i += 256) hist[i] = 0;
    __syncthreads();
    int base = blockIdx.x * CHUNK;
    int lim = base + CHUNK; if (lim > E) lim = E;
    for (int i = base + threadIdx.x; i < lim; i += 256) {
        int row = rows[i];
        int r = row / NNODES;                // magic-mul
        int n = row - r * NNODES;
        atomicAdd(&hist[n >> 7], 1);
    }
    __syncthreads();
    for (int i = threadIdx.x; i < NBUCK; i += 256)
        if (hist[i]) atomicAdd(&gcnt[i], hist[i]);
}

// ---------------------------------------------------------------------------
// Pass 2: exclusive scan of bucket counts -> bkt_off[NBUCK+1] + reserve cursors
// ---------------------------------------------------------------------------
__global__ __launch_bounds__(1024) void k_offsets(const int* __restrict__ gcnt,
                                                  int* __restrict__ bkt_off,
                                                  int* __restrict__ cursor) {
    __shared__ int tmp[1024];
    int t = threadIdx.x;
    int v = (t < NBUCK) ? gcnt[t] : 0;
    tmp[t] = v;
    __syncthreads();
    for (int d = 1; d < 1024; d <<= 1) {
        int u = (t >= d) ? tmp[t - d] : 0;
        __syncthreads();
        tmp[t] += u;
        __syncthreads();
    }
    if (t < NBUCK) {
        int excl = tmp[t] - v;
        bkt_off[t] = excl;
        cursor[t]  = excl;
    }
    if (t == 1023) bkt_off[NBUCK] = tmp[1023];
}

// ---------------------------------------------------------------------------
// Pass 3: partitioned scatter. Block = 4096 edges: LDS hist -> LDS scan ->
// one reserve atomic per (block,bucket) -> stage (key,delta) partitioned in
// LDS -> copy out with consecutive threads hitting consecutive addresses.
// Key = c<<3 | r | nloc<<20  (c<2^17, nloc = n&127).
// ---------------------------------------------------------------------------
__global__ __launch_bounds__(1024) void k_scatter2(const int* __restrict__ rows,
                                                   const int* __restrict__ cols,
                                                   int* __restrict__ cursor,
                                                   int* __restrict__ keys, int E) {
    __shared__ int hist[NBUCK];
    __shared__ int loff[NBUCK];
    __shared__ int dlt[NBUCK];
    __shared__ int cur[NBUCK];
    __shared__ int2 stg[CHUNK];
    __shared__ int tmp[1024];
    const int t = threadIdx.x;
    const int base = blockIdx.x * CHUNK;
    int m = E - base; if (m > CHUNK) m = CHUNK;

    for (int i = t; i < NBUCK; i += 1024) { hist[i] = 0; cur[i] = 0; }
    __syncthreads();

    int key[4], bk[4];
#pragma unroll
    for (int q = 0; q < 4; ++q) {
        int i = t + q * 1024;
        bk[q] = -1;
        if (i < m) {
            int row = rows[base + i];
            int c   = cols[base + i];
            int r = row / NNODES;
            int n = row - r * NNODES;
            bk[q]  = n >> 7;
            key[q] = (c << 3) | r | ((n & 127) << 20);
            atomicAdd(&hist[bk[q]], 1);
        }
    }
    __syncthreads();

    int v = (t < NBUCK) ? hist[t] : 0;
    tmp[t] = v;
    __syncthreads();
    for (int d = 1; d < 1024; d <<= 1) {
        int u = (t >= d) ? tmp[t - d] : 0;
        __syncthreads();
        tmp[t] += u;
        __syncthreads();
    }
    if (t < NBUCK) {
        int excl = tmp[t] - v;
        loff[t] = excl;
        int gb = (v > 0) ? atomicAdd(&cursor[t], v) : 0;
        dlt[t] = gb - excl;
    }
    __syncthreads();

#pragma unroll
    for (int q = 0; q < 4; ++q) {
        if (bk[q] >= 0) {
            int p = loff[bk[q]] + atomicAdd(&cur[bk[q]], 1);
            stg[p] = make_int2(key[q], dlt[bk[q]]);
        }
    }
    __syncthreads();

    for (int i = t; i < m; i += 1024) {
        int2 s = stg[i];
        keys[s.y + i] = s.x;
    }
}

// ---------------------------------------------------------------------------
// W prep (unchanged from round 12): pack W into MFMA A-fragment order.
// ---------------------------------------------------------------------------
__global__ void k_wprep(const float* __restrict__ W, unsigned short* __restrict__ wp) {
    int t = blockIdx.x * blockDim.x + threadIdx.x;   // 0..4095
    int lane = t & 63, ks = (t >> 6) & 1, ft = (t >> 7) & 3, rel = t >> 9;
    const float* src = W + rel * 4096 + (ks * 32 + (lane >> 4) * 8) * EMB
                       + ft * 16 + (lane & 15);
    bf16x8 o;
#pragma unroll
    for (int j = 0; j < 8; ++j) o[j] = (short)f2bf(src[j * EMB]);
    *reinterpret_cast<bf16x8*>(wp + (size_t)t * 8) = o;
}

// ---------------------------------------------------------------------------
// GEMM1 (unchanged from round 12): y[c, r*64+f] = sum_k x[c,k] * W[r,k,f].
// ---------------------------------------------------------------------------
__global__ __launch_bounds__(512) void k_gemm1(const float* __restrict__ x,
                                               const unsigned short* __restrict__ wp,
                                               unsigned short* __restrict__ y) {
    __shared__ char tile[2][16384];        // bf16 [16][512], swizzled, x2 buffers
    const int tid  = threadIdx.x;
    const int lane = tid & 63;
    const int rel  = tid >> 6;             // wave id = relation
    const int fl   = lane & 15;            // A row (f_local) == B col (c_local)
    const int kgrp = lane >> 4;            // k-group 0..3

    bf16x8 wfrag[4][2];
#pragma unroll
    for (int ft = 0; ft < 4; ++ft)
#pragma unroll
        for (int ks = 0; ks < 2; ++ks)
            wfrag[ft][ks] = *reinterpret_cast<const bf16x8*>(
                wp + (size_t)((rel * 4 + ft) * 2 + ks) * 512 + lane * 8);

    const int wbase = (fl << 10) + (rel << 7) + (kgrp << 3);
    const int wswz  = (fl & 7) << 4;
    int b = 0;

    int strip = blockIdx.x;
    const float* xp = x + (size_t)(strip * 16 + fl) * EMB + kgrp * 8;
    f32x4 xa0 = *reinterpret_cast<const f32x4*>(xp);
    f32x4 xa1 = *reinterpret_cast<const f32x4*>(xp + 4);
    f32x4 xa2 = *reinterpret_cast<const f32x4*>(xp + 32);
    f32x4 xa3 = *reinterpret_cast<const f32x4*>(xp + 36);

    while (strip < NSTRIPS) {
        const int next = strip + G1_BLOCKS;
        f32x4 xn0 = xa0, xn1 = xa1, xn2 = xa2, xn3 = xa3;
        if (next < NSTRIPS) {              // prefetch next strip's x rows
            const float* xq = x + (size_t)(next * 16 + fl) * EMB + kgrp * 8;
            xn0 = *reinterpret_cast<const f32x4*>(xq);
            xn1 = *reinterpret_cast<const f32x4*>(xq + 4);
            xn2 = *reinterpret_cast<const f32x4*>(xq + 32);
            xn3 = *reinterpret_cast<const f32x4*>(xq + 36);
        }

        bf16x8 B0, B1;
#pragma unroll
        for (int j = 0; j < 4; ++j) {
            B0[j] = (short)f2bf(xa0[j]);  B0[j + 4] = (short)f2bf(xa1[j]);
            B1[j] = (short)f2bf(xa2[j]);  B1[j + 4] = (short)f2bf(xa3[j]);
        }

        f32x4 acc[4] = {f32x4{}, f32x4{}, f32x4{}, f32x4{}};
#pragma unroll
        for (int ft = 0; ft < 4; ++ft) {
            acc[ft] = __builtin_amdgcn_mfma_f32_16x16x32_bf16(wfrag[ft][0], B0, acc[ft], 0, 0, 0);
            acc[ft] = __builtin_amdgcn_mfma_f32_16x16x32_bf16(wfrag[ft][1], B1, acc[ft], 0, 0, 0);
        }

        // D[f][c] -> LDS bf16 tile at [c_local=fl][f_glob=rel*64+ft*16+kgrp*4+i]
        char* tb = tile[b];
#pragma unroll
        for (int ft = 0; ft < 4; ++ft) {
            ushort4 o;
            o.x = f2bf(acc[ft][0]); o.y = f2bf(acc[ft][1]);
            o.z = f2bf(acc[ft][2]); o.w = f2bf(acc[ft][3]);
            *reinterpret_cast<ushort4*>(tb + ((wbase + (ft << 5)) ^ wswz)) = o;
        }

        // raw barrier: wait LDS only, do NOT drain global stores (vmcnt)
        __builtin_amdgcn_sched_barrier(0);
        asm volatile("s_waitcnt lgkmcnt(0)" ::: "memory");
        __builtin_amdgcn_s_barrier();
        __builtin_amdgcn_sched_barrier(0);

        // stream tile -> y, fully coalesced 16B/lane, fire-and-forget
#pragma unroll
        for (int h = 0; h < 2; ++h) {
            int u  = tid + h * 512;            // 16B unit 0..1023
            int cl = u >> 6;                   // c_local
            bf16x8 v = *reinterpret_cast<const bf16x8*>(tb + ((u << 4) ^ ((cl & 7) << 4)));
            *reinterpret_cast<bf16x8*>(y + (size_t)(strip * 16 + cl) * YDIM + ((u & 63) << 3)) = v;
        }
        b ^= 1;   // buffer reuse at distance 2 is protected by the barrier chain
        xa0 = xn0; xa1 = xn1; xa2 = xn2; xa3 = xn3;
        strip = next;
    }
}

// ---------------------------------------------------------------------------
// Gather: block = one 128-node bucket (256 thr / 4 waves). Stage the bucket's
// keys (exact count from bkt_off), build per-node CSR in LDS, then wave w
// processes nodes w*32..w*32+31: ballot per-rel degree, 8-deep readlane
// y-gather, out = relu(acc) f32.
// ---------------------------------------------------------------------------
__global__ __launch_bounds__(256) void k_gather(const int* __restrict__ bkt_off,
                                                const int* __restrict__ keys,
                                                const unsigned short* __restrict__ yb,
                                                float* __restrict__ out) {
    __shared__ int raw[2048];
    __shared__ int srt[2048];
    __shared__ int cntL[GNODES], offL[GNODES], curL[GNODES];

    const int bkt  = blockIdx.x;
    const int tid  = threadIdx.x;
    const int lane = tid & 63;
    const int wid  = tid >> 6;

    const int s0 = bkt_off[bkt];
    int m = bkt_off[bkt + 1] - s0;
    if (m > 2048) m = 2048;               // unreachable (lambda=1280, 2048=+21sig)

    for (int i = tid; i < m; i += 256) raw[i] = keys[s0 + i];
    if (tid < GNODES) cntL[tid] = 0;
    __syncthreads();

    for (int i = tid; i < m; i += 256) atomicAdd(&cntL[raw[i] >> 20], 1);
    __syncthreads();

    if (wid == 0) {                        // exclusive scan of 128 counts
        int v0 = cntL[lane], v1 = cntL[lane + 64];
        int a0 = v0, a1 = v1;
#pragma unroll
        for (int d = 1; d < 64; d <<= 1) {
            int u0 = __shfl_up(a0, d); if (lane >= d) a0 += u0;
            int u1 = __shfl_up(a1, d); if (lane >= d) a1 += u1;
        }
        int tot0 = __shfl(a0, 63);
        offL[lane]      = a0 - v0;        curL[lane]      = a0 - v0;
        offL[lane + 64] = tot0 + a1 - v1; curL[lane + 64] = tot0 + a1 - v1;
    }
    __syncthreads();

    for (int i = tid; i < m; i += 256) {
        int k = raw[i];
        int p = atomicAdd(&curL[k >> 20], 1);
        srt[p] = k;
    }
    __syncthreads();

    const int nbase = bkt * GNODES;
    int nlim = NNODES - nbase; if (nlim > GNODES) nlim = GNODES;
    for (int i = wid * 32; i < wid * 32 + 32; ++i) {
        if (i >= nlim) break;
        int s = offL[i], d = cntL[i];
        if (d > 64) d = 64;                 // safety; per-node degree ~Poisson(10)
        int kv = (lane < d) ? srt[s + lane] : -1;

        // per-relation degree via ballots (r = low 3 bits of key)
        int crv = 0;
        const int myr = lane & 7;
#pragma unroll
        for (int r = 0; r < NREL; ++r) {
            int cr = (int)__popcll(__ballot(kv >= 0 && (kv & 7) == r));
            crv = (myr == r) ? cr : crv;
        }
        float inv8 = (crv > 0) ? __builtin_amdgcn_rcpf((float)crv) : 0.f;
        int inv8b = __float_as_int(inv8);

        float acc = 0.f;
        for (int j0 = 0; j0 < d; j0 += 8) {
#pragma unroll
            for (int u = 0; u < 8; ++u) {
                int j  = j0 + u;
                int jc = j < d ? j : 0;                         // uniform clamp
                int sp = __builtin_amdgcn_readlane(kv, jc) & 0xFFFFF;  // y-row c*8+r
                int ib = __builtin_amdgcn_readlane(inv8b, sp & 7);
                float si = (j < d) ? __int_as_float(ib) : 0.f;  // dead edge -> *0
                float v  = bf2f(yb[(size_t)sp * EMB + lane]);
                acc = fmaf(si, v, acc);
            }
        }
        out[(size_t)(nbase + i) * EMB + lane] = fmaxf(acc, 0.f);
    }
}

// ---------------------------------------------------------------------------
extern "C" void kernel_launch(void* const* d_in, const int* in_sizes, int n_in,
                              void* d_out, int out_size, void* d_ws, size_t ws_size,
                              hipStream_t stream) {
    const float* x    = (const float*)d_in[0];
    const float* w    = (const float*)d_in[1];
    const int*   rows = (const int*)d_in[2];   // JAX x64-disabled -> int32
    const int*   cols = (const int*)d_in[3];
    float*       out  = (float*)d_out;
    int E = in_sizes[2];

    char* ws = (char*)d_ws;
    int*            gcnt    = (int*)(ws);                       // 4 KB region
    int*            bkt_off = (int*)(ws + 4096);                // 4 KB region
    int*            cursor  = (int*)(ws + 8192);                // 4 KB region
    int*            keys    = (int*)(ws + 12288);               // 4 MB
    unsigned short* wp      = (unsigned short*)(ws + 4206592);  // 64 KB
    unsigned short* y       = (unsigned short*)(ws + 4272128);  // 102.4 MB

    hipMemsetAsync(gcnt, 0, (size_t)NBUCK * sizeof(int), stream);

    int eb = (E + CHUNK - 1) / CHUNK;     // 245
    k_wprep<<<16, 256, 0, stream>>>(w, wp);
    k_count<<<eb, 256, 0, stream>>>(rows, gcnt, E);
    k_offsets<<<1, 1024, 0, stream>>>(gcnt, bkt_off, cursor);
    k_scatter2<<<eb, 1024, 0, stream>>>(rows, cols, cursor, keys, E);
    k_gemm1<<<G1_BLOCKS, 512, 0, stream>>>(x, wp, y);
    k_gather<<<NBUCK, 256, 0, stream>>>(bkt_off, keys, y, out);
}

// Round 15
// 127.738 us; speedup vs baseline: 1.9839x; 1.0967x over previous
//
#include <hip/hip_runtime.h>

#define NNODES 100000
#define NREL 8
#define EMB 64
#define YDIM (NREL * EMB)            // 512
#define NSTRIPS (NNODES / 16)        // 6250, exact
#define G1_BLOCKS 1250               // 5 strips per block, exact
#define GNODES 128                   // nodes per coarse bucket
#define NBUCK 782                    // ceil(NNODES/128)
#define CHUNK 4096                   // edges per scatter block

typedef __attribute__((ext_vector_type(8))) short bf16x8;   // 8 bf16 (4 VGPRs)
typedef __attribute__((ext_vector_type(4))) float f32x4;

__device__ inline unsigned short f2bf(float f) {
    union { float f; unsigned u; } v; v.f = f;
    return (unsigned short)((v.u + 0x7FFFu + ((v.u >> 16) & 1u)) >> 16);  // RNE
}
__device__ inline float bf2f(unsigned short u) {
    union { unsigned u; float f; } v; v.u = ((unsigned)u) << 16; return v.f;
}

// ---------------------------------------------------------------------------
// Pass 1: exact bucket histogram (LDS-aggregated; ~245 global atomics/counter)
// ---------------------------------------------------------------------------
__global__ __launch_bounds__(256) void k_count(const int* __restrict__ rows,
                                               int* __restrict__ gcnt, int E) {
    __shared__ int hist[NBUCK];
    for (int i = threadIdx.x; i < NBUCK; i += 256) hist[i] = 0;
    __syncthreads();
    int base = blockIdx.x * CHUNK;
    int lim = base + CHUNK; if (lim > E) lim = E;
    for (int i = base + threadIdx.x; i < lim; i += 256) {
        int row = rows[i];
        int r = row / NNODES;                // magic-mul
        int n = row - r * NNODES;
        atomicAdd(&hist[n >> 7], 1);
    }
    __syncthreads();
    for (int i = threadIdx.x; i < NBUCK; i += 256)
        if (hist[i]) atomicAdd(&gcnt[i], hist[i]);
}

// ---------------------------------------------------------------------------
// Pass 2: exclusive scan of bucket counts -> bkt_off[NBUCK+1] + reserve cursors
// ---------------------------------------------------------------------------
__global__ __launch_bounds__(1024) void k_offsets(const int* __restrict__ gcnt,
                                                  int* __restrict__ bkt_off,
                                                  int* __restrict__ cursor) {
    __shared__ int tmp[1024];
    int t = threadIdx.x;
    int v = (t < NBUCK) ? gcnt[t] : 0;
    tmp[t] = v;
    __syncthreads();
    for (int d = 1; d < 1024; d <<= 1) {
        int u = (t >= d) ? tmp[t - d] : 0;
        __syncthreads();
        tmp[t] += u;
        __syncthreads();
    }
    if (t < NBUCK) {
        int excl = tmp[t] - v;
        bkt_off[t] = excl;
        cursor[t]  = excl;
    }
    if (t == 1023) bkt_off[NBUCK] = tmp[1023];
}

// ---------------------------------------------------------------------------
// Pass 3: partitioned scatter. Block = 4096 edges: LDS hist -> LDS scan ->
// one reserve atomic per (block,bucket) -> stage (key,delta) partitioned in
// LDS -> copy out with consecutive threads hitting consecutive addresses.
// Key = c<<3 | r | nloc<<20  (c<2^17, nloc = n&127).
// ---------------------------------------------------------------------------
__global__ __launch_bounds__(1024) void k_scatter2(const int* __restrict__ rows,
                                                   const int* __restrict__ cols,
                                                   int* __restrict__ cursor,
                                                   int* __restrict__ keys, int E) {
    __shared__ int hist[NBUCK];
    __shared__ int loff[NBUCK];
    __shared__ int dlt[NBUCK];
    __shared__ int cur[NBUCK];
    __shared__ int2 stg[CHUNK];
    __shared__ int tmp[1024];
    const int t = threadIdx.x;
    const int base = blockIdx.x * CHUNK;
    int m = E - base; if (m > CHUNK) m = CHUNK;

    for (int i = t; i < NBUCK; i += 1024) { hist[i] = 0; cur[i] = 0; }
    __syncthreads();

    int key[4], bk[4];
#pragma unroll
    for (int q = 0; q < 4; ++q) {
        int i = t + q * 1024;
        bk[q] = -1;
        if (i < m) {
            int row = rows[base + i];
            int c   = cols[base + i];
            int r = row / NNODES;
            int n = row - r * NNODES;
            bk[q]  = n >> 7;
            key[q] = (c << 3) | r | ((n & 127) << 20);
            atomicAdd(&hist[bk[q]], 1);
        }
    }
    __syncthreads();

    int v = (t < NBUCK) ? hist[t] : 0;
    tmp[t] = v;
    __syncthreads();
    for (int d = 1; d < 1024; d <<= 1) {
        int u = (t >= d) ? tmp[t - d] : 0;
        __syncthreads();
        tmp[t] += u;
        __syncthreads();
    }
    if (t < NBUCK) {
        int excl = tmp[t] - v;
        loff[t] = excl;
        int gb = (v > 0) ? atomicAdd(&cursor[t], v) : 0;
        dlt[t] = gb - excl;
    }
    __syncthreads();

#pragma unroll
    for (int q = 0; q < 4; ++q) {
        if (bk[q] >= 0) {
            int p = loff[bk[q]] + atomicAdd(&cur[bk[q]], 1);
            stg[p] = make_int2(key[q], dlt[bk[q]]);
        }
    }
    __syncthreads();

    for (int i = t; i < m; i += 1024) {
        int2 s = stg[i];
        keys[s.y + i] = s.x;
    }
}

// ---------------------------------------------------------------------------
// W prep (unchanged): pack W into MFMA A-fragment order.
// ---------------------------------------------------------------------------
__global__ void k_wprep(const float* __restrict__ W, unsigned short* __restrict__ wp) {
    int t = blockIdx.x * blockDim.x + threadIdx.x;   // 0..4095
    int lane = t & 63, ks = (t >> 6) & 1, ft = (t >> 7) & 3, rel = t >> 9;
    const float* src = W + rel * 4096 + (ks * 32 + (lane >> 4) * 8) * EMB
                       + ft * 16 + (lane & 15);
    bf16x8 o;
#pragma unroll
    for (int j = 0; j < 8; ++j) o[j] = (short)f2bf(src[j * EMB]);
    *reinterpret_cast<bf16x8*>(wp + (size_t)t * 8) = o;
}

// ---------------------------------------------------------------------------
// GEMM1 (unchanged): y[c, r*64+f] = sum_k x[c,k] * W[r,k,f].
// ---------------------------------------------------------------------------
__global__ __launch_bounds__(512) void k_gemm1(const float* __restrict__ x,
                                               const unsigned short* __restrict__ wp,
                                               unsigned short* __restrict__ y) {
    __shared__ char tile[2][16384];        // bf16 [16][512], swizzled, x2 buffers
    const int tid  = threadIdx.x;
    const int lane = tid & 63;
    const int rel  = tid >> 6;             // wave id = relation
    const int fl   = lane & 15;            // A row (f_local) == B col (c_local)
    const int kgrp = lane >> 4;            // k-group 0..3

    bf16x8 wfrag[4][2];
#pragma unroll
    for (int ft = 0; ft < 4; ++ft)
#pragma unroll
        for (int ks = 0; ks < 2; ++ks)
            wfrag[ft][ks] = *reinterpret_cast<const bf16x8*>(
                wp + (size_t)((rel * 4 + ft) * 2 + ks) * 512 + lane * 8);

    const int wbase = (fl << 10) + (rel << 7) + (kgrp << 3);
    const int wswz  = (fl & 7) << 4;
    int b = 0;

    int strip = blockIdx.x;
    const float* xp = x + (size_t)(strip * 16 + fl) * EMB + kgrp * 8;
    f32x4 xa0 = *reinterpret_cast<const f32x4*>(xp);
    f32x4 xa1 = *reinterpret_cast<const f32x4*>(xp + 4);
    f32x4 xa2 = *reinterpret_cast<const f32x4*>(xp + 32);
    f32x4 xa3 = *reinterpret_cast<const f32x4*>(xp + 36);

    while (strip < NSTRIPS) {
        const int next = strip + G1_BLOCKS;
        f32x4 xn0 = xa0, xn1 = xa1, xn2 = xa2, xn3 = xa3;
        if (next < NSTRIPS) {              // prefetch next strip's x rows
            const float* xq = x + (size_t)(next * 16 + fl) * EMB + kgrp * 8;
            xn0 = *reinterpret_cast<const f32x4*>(xq);
            xn1 = *reinterpret_cast<const f32x4*>(xq + 4);
            xn2 = *reinterpret_cast<const f32x4*>(xq + 32);
            xn3 = *reinterpret_cast<const f32x4*>(xq + 36);
        }

        bf16x8 B0, B1;
#pragma unroll
        for (int j = 0; j < 4; ++j) {
            B0[j] = (short)f2bf(xa0[j]);  B0[j + 4] = (short)f2bf(xa1[j]);
            B1[j] = (short)f2bf(xa2[j]);  B1[j + 4] = (short)f2bf(xa3[j]);
        }

        f32x4 acc[4] = {f32x4{}, f32x4{}, f32x4{}, f32x4{}};
#pragma unroll
        for (int ft = 0; ft < 4; ++ft) {
            acc[ft] = __builtin_amdgcn_mfma_f32_16x16x32_bf16(wfrag[ft][0], B0, acc[ft], 0, 0, 0);
            acc[ft] = __builtin_amdgcn_mfma_f32_16x16x32_bf16(wfrag[ft][1], B1, acc[ft], 0, 0, 0);
        }

        // D[f][c] -> LDS bf16 tile at [c_local=fl][f_glob=rel*64+ft*16+kgrp*4+i]
        char* tb = tile[b];
#pragma unroll
        for (int ft = 0; ft < 4; ++ft) {
            ushort4 o;
            o.x = f2bf(acc[ft][0]); o.y = f2bf(acc[ft][1]);
            o.z = f2bf(acc[ft][2]); o.w = f2bf(acc[ft][3]);
            *reinterpret_cast<ushort4*>(tb + ((wbase + (ft << 5)) ^ wswz)) = o;
        }

        // raw barrier: wait LDS only, do NOT drain global stores (vmcnt)
        __builtin_amdgcn_sched_barrier(0);
        asm volatile("s_waitcnt lgkmcnt(0)" ::: "memory");
        __builtin_amdgcn_s_barrier();
        __builtin_amdgcn_sched_barrier(0);

        // stream tile -> y, fully coalesced 16B/lane, fire-and-forget
#pragma unroll
        for (int h = 0; h < 2; ++h) {
            int u  = tid + h * 512;            // 16B unit 0..1023
            int cl = u >> 6;                   // c_local
            bf16x8 v = *reinterpret_cast<const bf16x8*>(tb + ((u << 4) ^ ((cl & 7) << 4)));
            *reinterpret_cast<bf16x8*>(y + (size_t)(strip * 16 + cl) * YDIM + ((u & 63) << 3)) = v;
        }
        b ^= 1;   // buffer reuse at distance 2 is protected by the barrier chain
        xa0 = xn0; xa1 = xn1; xa2 = xn2; xa3 = xn3;
        strip = next;
    }
}

// ---------------------------------------------------------------------------
// Gather: block = one 128-node bucket, 1024 thr / 16 waves (was 256/4 --
// occupancy fix: 2 blocks/CU = 32 waves/CU vs 12). Stage keys, build per-node
// CSR in LDS, then wave w processes nodes w*8..w*8+7: ballot per-rel degree,
// 8-deep readlane y-gather, out = relu(acc) f32.
// ---------------------------------------------------------------------------
__global__ __launch_bounds__(1024) void k_gather(const int* __restrict__ bkt_off,
                                                 const int* __restrict__ keys,
                                                 const unsigned short* __restrict__ yb,
                                                 float* __restrict__ out) {
    __shared__ int raw[2048];
    __shared__ int srt[2048];
    __shared__ int cntL[GNODES], offL[GNODES], curL[GNODES];

    const int bkt  = blockIdx.x;
    const int tid  = threadIdx.x;
    const int lane = tid & 63;
    const int wid  = tid >> 6;

    const int s0 = bkt_off[bkt];
    int m = bkt_off[bkt + 1] - s0;
    if (m > 2048) m = 2048;               // unreachable (lambda=1280, 2048=+21sig)

    for (int i = tid; i < m; i += 1024) raw[i] = keys[s0 + i];
    if (tid < GNODES) cntL[tid] = 0;
    __syncthreads();

    for (int i = tid; i < m; i += 1024) atomicAdd(&cntL[raw[i] >> 20], 1);
    __syncthreads();

    if (wid == 0) {                        // exclusive scan of 128 counts
        int v0 = cntL[lane], v1 = cntL[lane + 64];
        int a0 = v0, a1 = v1;
#pragma unroll
        for (int d = 1; d < 64; d <<= 1) {
            int u0 = __shfl_up(a0, d); if (lane >= d) a0 += u0;
            int u1 = __shfl_up(a1, d); if (lane >= d) a1 += u1;
        }
        int tot0 = __shfl(a0, 63);
        offL[lane]      = a0 - v0;        curL[lane]      = a0 - v0;
        offL[lane + 64] = tot0 + a1 - v1; curL[lane + 64] = tot0 + a1 - v1;
    }
    __syncthreads();

    for (int i = tid; i < m; i += 1024) {
        int k = raw[i];
        int p = atomicAdd(&curL[k >> 20], 1);
        srt[p] = k;
    }
    __syncthreads();

    const int nbase = bkt * GNODES;
    int nlim = NNODES - nbase; if (nlim > GNODES) nlim = GNODES;
    for (int i = wid * 8; i < wid * 8 + 8; ++i) {
        if (i >= nlim) break;
        int s = offL[i], d = cntL[i];
        if (d > 64) d = 64;                 // safety; per-node degree ~Poisson(10)
        int kv = (lane < d) ? srt[s + lane] : -1;

        // per-relation degree via ballots (r = low 3 bits of key)
        int crv = 0;
        const int myr = lane & 7;
#pragma unroll
        for (int r = 0; r < NREL; ++r) {
            int cr = (int)__popcll(__ballot(kv >= 0 && (kv & 7) == r));
            crv = (myr == r) ? cr : crv;
        }
        float inv8 = (crv > 0) ? __builtin_amdgcn_rcpf((float)crv) : 0.f;
        int inv8b = __float_as_int(inv8);

        float acc = 0.f;
        for (int j0 = 0; j0 < d; j0 += 8) {
#pragma unroll
            for (int u = 0; u < 8; ++u) {
                int j  = j0 + u;
                int jc = j < d ? j : 0;                         // uniform clamp
                int sp = __builtin_amdgcn_readlane(kv, jc) & 0xFFFFF;  // y-row c*8+r
                int ib = __builtin_amdgcn_readlane(inv8b, sp & 7);
                float si = (j < d) ? __int_as_float(ib) : 0.f;  // dead edge -> *0
                float v  = bf2f(yb[(size_t)sp * EMB + lane]);
                acc = fmaf(si, v, acc);
            }
        }
        out[(size_t)(nbase + i) * EMB + lane] = fmaxf(acc, 0.f);
    }
}

// ---------------------------------------------------------------------------
extern "C" void kernel_launch(void* const* d_in, const int* in_sizes, int n_in,
                              void* d_out, int out_size, void* d_ws, size_t ws_size,
                              hipStream_t stream) {
    const float* x    = (const float*)d_in[0];
    const float* w    = (const float*)d_in[1];
    const int*   rows = (const int*)d_in[2];   // JAX x64-disabled -> int32
    const int*   cols = (const int*)d_in[3];
    float*       out  = (float*)d_out;
    int E = in_sizes[2];

    char* ws = (char*)d_ws;
    int*            gcnt    = (int*)(ws);                       // 4 KB region
    int*            bkt_off = (int*)(ws + 4096);                // 4 KB region
    int*            cursor  = (int*)(ws + 8192);                // 4 KB region
    int*            keys    = (int*)(ws + 12288);               // 4 MB
    unsigned short* wp      = (unsigned short*)(ws + 4206592);  // 64 KB
    unsigned short* y       = (unsigned short*)(ws + 4272128);  // 102.4 MB

    hipMemsetAsync(gcnt, 0, (size_t)NBUCK * sizeof(int), stream);

    int eb = (E + CHUNK - 1) / CHUNK;     // 245
    k_wprep<<<16, 256, 0, stream>>>(w, wp);
    k_count<<<eb, 256, 0, stream>>>(rows, gcnt, E);
    k_offsets<<<1, 1024, 0, stream>>>(gcnt, bkt_off, cursor);
    k_scatter2<<<eb, 1024, 0, stream>>>(rows, cols, cursor, keys, E);
    k_gemm1<<<G1_BLOCKS, 512, 0, stream>>>(x, wp, y);
    k_gather<<<NBUCK, 1024, 0, stream>>>(bkt_off, keys, y, out);
}